// Round 2
// baseline (807.292 us; speedup 1.0000x reference)
//
#include <hip/hip_runtime.h>
#include <math.h>

// Problem constants
#define D    256      // feature dim (= C)
#define K    1024     // codebook size
#define HWX  1024     // H*W
#define NPTS 32768    // B*H*W

// Tiling: block = 256 threads, 32 points x 512 codes per k-tile
// thread microtile = 8 points x 8 codes (64 fp32 accumulators)
#define PT   32       // points per block
#define KT   512      // codes per k-tile (2 tiles cover K)
#define DCH  8        // d per stage
#define XSTR 2052     // x-tile row stride per point-group (256*8 + 4 floats)
#define ESTR 576      // e-tile row stride: 512 cols + 4-float pad per 32 cols

#define Q_OFF    1
#define PERP_OFF (1 + 8388608)
#define ENC_OFF  (2 + 8388608)

// ws layout: enorm float[1024] @0 ; counts int[1024] @4096B ; loss_accum float @8192B

__global__ __launch_bounds__(256) void vq_prep(const float* __restrict__ emb,
                                               float* __restrict__ enorm,
                                               int* __restrict__ counts,
                                               float* __restrict__ loss_accum) {
  const int t = threadIdx.x;
  const int gid = blockIdx.x * 256 + t;
  const int w = gid >> 6;          // code id, 0..1023 (grid = 256 blocks)
  const int lane = t & 63;
  float4 v = *reinterpret_cast<const float4*>(emb + (size_t)w * D + lane * 4);
  float s = v.x * v.x + v.y * v.y + v.z * v.z + v.w * v.w;
#pragma unroll
  for (int off = 32; off > 0; off >>= 1) s += __shfl_down(s, off);
  if (lane == 0) enorm[w] = s;
  if (gid < K) counts[gid] = 0;
  if (gid == 0) *loss_accum = 0.0f;
}

// acc[p][q] += x[p] * e[q] for one d
#define FMA8x8(XP0, XP1, EV0, EV1)                                            \
  {                                                                           \
    const float eq[8] = {EV0.x, EV0.y, EV0.z, EV0.w,                          \
                         EV1.x, EV1.y, EV1.z, EV1.w};                         \
    _Pragma("unroll") for (int q = 0; q < 8; ++q) {                           \
      acc[0][q] += XP0.x * eq[q]; acc[1][q] += XP0.y * eq[q];                 \
      acc[2][q] += XP0.z * eq[q]; acc[3][q] += XP0.w * eq[q];                 \
      acc[4][q] += XP1.x * eq[q]; acc[5][q] += XP1.y * eq[q];                 \
      acc[6][q] += XP1.z * eq[q]; acc[7][q] += XP1.w * eq[q];                 \
    }                                                                         \
  }

__global__ __launch_bounds__(256, 3) void vq_main(const float* __restrict__ x,
                                                  const float* __restrict__ emb,
                                                  const float* __restrict__ enorm,
                                                  float* __restrict__ out_q,
                                                  float* __restrict__ out_enc,
                                                  float* __restrict__ loss_accum,
                                                  int* __restrict__ counts) {
  __shared__ float xs[4 * XSTR];     // 32832 B: x tile [pg][d*8 + j], full D
  __shared__ float es[DCH * ESTR];   // 18432 B: transposed e tile [dd][col(code)]
  __shared__ int idx_s[PT];

  const int t = threadIdx.x;
  const int p0 = blockIdx.x * PT;   // first point of this block
  const int bb = p0 >> 10;          // batch index
  const int hw0 = p0 & 1023;        // hw offset (PT-aligned)
  const int pg = t & 3;             // point group (8 points each)
  const int kg = t >> 2;            // 0..63, 8 codes each

  // ---- stage x tile: NCHW -> LDS [pg][d*8+j] (coalesced 128B segments) ----
  {
    const int pi = t & 31, c0 = t >> 5;
    const int xj = pi & 7, xpg = pi >> 3;
    const float* xb = x + (size_t)bb * D * HWX + hw0 + pi;
#pragma unroll
    for (int c = c0; c < D; c += 8)
      xs[xpg * XSTR + c * 8 + xj] = xb[(size_t)c * HWX];
  }

  // e-stage prefetch assignment: 2 lanes per code row chunk (DCH=8 floats)
  const int pf_code = t >> 1;        // 0..127
  const int pf_dl = (t & 1) * 4;     // 0 or 4
  float4 pf[4];
  auto load_stage = [&](int s) {
    const int k0 = (s >> 5) * KT;
    const int dc = (s & 31) * DCH;
    const float* base = emb + (size_t)(k0 + pf_code) * D + dc + pf_dl;
    pf[0] = *reinterpret_cast<const float4*>(base);
    pf[1] = *reinterpret_cast<const float4*>(base + 128 * D);
    pf[2] = *reinterpret_cast<const float4*>(base + 256 * D);
    pf[3] = *reinterpret_cast<const float4*>(base + 384 * D);
  };
  load_stage(0);

  const int col8 = kg * 8 + ((kg >> 2) << 2);  // my 8 codes' physical column

  float minval[8];
  int minidx[8];
#pragma unroll
  for (int p = 0; p < 8; ++p) { minval[p] = 3.4e38f; minidx[p] = 0; }

  for (int kt = 0; kt < K / KT; ++kt) {
    float acc[8][8];
#pragma unroll
    for (int p = 0; p < 8; ++p)
#pragma unroll
      for (int q = 0; q < 8; ++q) acc[p][q] = 0.0f;

    for (int dcb = 0; dcb < 32; ++dcb) {
      const int s = kt * 32 + dcb;
      const int dc = dcb * DCH;
      __syncthreads();  // prior readers done with es
      // write prefetched e chunk, transposed + swizzle-padded
#pragma unroll
      for (int i = 0; i < 4; ++i) {
        const int code = pf_code + i * 128;
        const int col = code + ((code >> 5) << 2);
        es[(pf_dl + 0) * ESTR + col] = pf[i].x;
        es[(pf_dl + 1) * ESTR + col] = pf[i].y;
        es[(pf_dl + 2) * ESTR + col] = pf[i].z;
        es[(pf_dl + 3) * ESTR + col] = pf[i].w;
      }
      if (s + 1 < 64) load_stage(s + 1);  // overlaps compute below
      __syncthreads();  // es ready
      const float* xb = xs + pg * XSTR + dc * 8;
      const float* eb = es + col8;
#pragma unroll
      for (int dd = 0; dd < DCH; ++dd) {
        const float4 xp0 = *reinterpret_cast<const float4*>(xb + dd * 8);
        const float4 xp1 = *reinterpret_cast<const float4*>(xb + dd * 8 + 4);
        const float4 ev0 = *reinterpret_cast<const float4*>(eb + dd * ESTR);
        const float4 ev1 = *reinterpret_cast<const float4*>(eb + dd * ESTR + 4);
        FMA8x8(xp0, xp1, ev0, ev1)
      }
    }
    // argmin update: dist = ||e||^2 - 2 x.e (x-norm row-constant)
    const int kbase = kt * KT + kg * 8;
    const float4 en0 = *reinterpret_cast<const float4*>(enorm + kbase);
    const float4 en1 = *reinterpret_cast<const float4*>(enorm + kbase + 4);
    const float en[8] = {en0.x, en0.y, en0.z, en0.w, en1.x, en1.y, en1.z, en1.w};
#pragma unroll
    for (int p = 0; p < 8; ++p)
#pragma unroll
      for (int q = 0; q < 8; ++q) {
        const float m = en[q] - 2.0f * acc[p][q];
        if (m < minval[p]) { minval[p] = m; minidx[p] = kbase + q; }
      }
  }

  // ---- cross-kg reduction (red arrays alias es) ----
  __syncthreads();
  float* red_val = es;                     // [64 kg][32 pi]
  int* red_idx = (int*)(es + 64 * PT);
#pragma unroll
  for (int p = 0; p < 8; ++p) {
    red_val[kg * PT + pg * 8 + p] = minval[p];
    red_idx[kg * PT + pg * 8 + p] = minidx[p];
  }
  __syncthreads();
  float dist = 0.0f;
  if (t < PT) {
    const int pi = t;
    float bv = red_val[pi];
    int bi = red_idx[pi];
    for (int g = 1; g < 64; ++g) {
      const float v = red_val[g * PT + pi];
      const int iv = red_idx[g * PT + pi];
      if (v < bv || (v == bv && iv < bi)) { bv = v; bi = iv; }  // first-index tie-break
    }
    // x-norm from LDS (2-way max aliasing)
    float xn = 0.0f;
    const float* xp = xs + (pi >> 3) * XSTR + (pi & 7);
    for (int d = 0; d < D; ++d) { const float xv = xp[d * 8]; xn += xv * xv; }
    dist = bv + xn;  // = ||x||^2 + ||e||^2 - 2 x.e
    idx_s[pi] = bi;
    atomicAdd(&counts[bi], 1);
  }
  if (t < 64) {  // full wave 0: lanes 32..63 contribute 0
#pragma unroll
    for (int off = 32; off > 0; off >>= 1) dist += __shfl_down(dist, off);
    if (t == 0) atomicAdd(loss_accum, dist);
  }
  __syncthreads();

  // ---- quantized output, NCHW (coalesced stores; emb gather is L2-hot) ----
  {
    const int pi = t & 31, c0 = t >> 5;
    const int row = idx_s[pi];
    const float* er = emb + (size_t)row * D;
    float* qb = out_q + (size_t)bb * D * HWX + hw0 + pi;
#pragma unroll
    for (int c = c0; c < D; c += 8) qb[(size_t)c * HWX] = er[c];
  }
  // ---- one-hot encodings (float2: enc region is only 8B-aligned) ----
  {
    float2* eb2 = reinterpret_cast<float2*>(out_enc + (size_t)p0 * K);
#pragma unroll 4
    for (int i = t; i < PT * K / 2; i += 256) {
      const int row = i >> 9;
      const int c2 = (i & 511) * 2;
      const int target = idx_s[row];
      float2 v = make_float2(0.f, 0.f);
      if (target == c2) v.x = 1.0f;
      else if (target == c2 + 1) v.y = 1.0f;
      eb2[i] = v;
    }
  }
}

__global__ __launch_bounds__(256) void vq_final(const int* __restrict__ counts,
                                                const float* __restrict__ loss_accum,
                                                float* __restrict__ out) {
  __shared__ float sh[4];
  const int t = threadIdx.x;
  float s = 0.0f;
  for (int k = t; k < K; k += 256) {
    const float p = (float)counts[k] * (1.0f / 32768.0f);
    s += p * logf(p + 1e-10f);  // p==0 -> contributes 0
  }
#pragma unroll
  for (int off = 32; off > 0; off >>= 1) s += __shfl_down(s, off);
  if ((t & 63) == 0) sh[t >> 6] = s;
  __syncthreads();
  if (t == 0) {
    const float tot = sh[0] + sh[1] + sh[2] + sh[3];
    out[PERP_OFF] = expf(-tot);
    out[0] = 0.25f * (*loss_accum) / 8388608.0f;
  }
}

extern "C" void kernel_launch(void* const* d_in, const int* in_sizes, int n_in,
                              void* d_out, int out_size, void* d_ws, size_t ws_size,
                              hipStream_t stream) {
  const float* x = (const float*)d_in[0];     // [32,256,32,32] fp32 NCHW
  const float* emb = (const float*)d_in[1];   // [1024,256] fp32
  float* out = (float*)d_out;
  float* enorm = (float*)d_ws;
  int* counts = (int*)((char*)d_ws + 4096);
  float* loss_accum = (float*)((char*)d_ws + 8192);

  hipLaunchKernelGGL(vq_prep, dim3(256), dim3(256), 0, stream,
                     emb, enorm, counts, loss_accum);
  hipLaunchKernelGGL(vq_main, dim3(NPTS / PT), dim3(256), 0, stream,
                     x, emb, enorm, out + Q_OFF, out + ENC_OFF, loss_accum, counts);
  hipLaunchKernelGGL(vq_final, dim3(1), dim3(256), 0, stream,
                     counts, loss_accum, out);
}